// Round 2
// baseline (491.073 us; speedup 1.0000x reference)
//
#include <hip/hip_runtime.h>

#define T 512
#define B 2
#define NH 16
#define FD 16
#define HD 64
#define DP 160
#define CH 64
#define NC 8

typedef __attribute__((ext_vector_type(4))) short short4v;
typedef __attribute__((ext_vector_type(8))) short bf16x8;
typedef __attribute__((ext_vector_type(4))) float f32x4;

__constant__ unsigned char c_iu[120] = {
0,0,0,0,0,0,0,0,0,0,0,0,0,0,0,
1,1,1,1,1,1,1,1,1,1,1,1,1,1,
2,2,2,2,2,2,2,2,2,2,2,2,2,
3,3,3,3,3,3,3,3,3,3,3,3,
4,4,4,4,4,4,4,4,4,4,4,
5,5,5,5,5,5,5,5,5,5,
6,6,6,6,6,6,6,6,6,
7,7,7,7,7,7,7,7,
8,8,8,8,8,8,8,
9,9,9,9,9,9,
10,10,10,10,10,
11,11,11,11,
12,12,12,
13,13,
14};
__constant__ unsigned char c_ju[120] = {
1,2,3,4,5,6,7,8,9,10,11,12,13,14,15,
2,3,4,5,6,7,8,9,10,11,12,13,14,15,
3,4,5,6,7,8,9,10,11,12,13,14,15,
4,5,6,7,8,9,10,11,12,13,14,15,
5,6,7,8,9,10,11,12,13,14,15,
6,7,8,9,10,11,12,13,14,15,
7,8,9,10,11,12,13,14,15,
8,9,10,11,12,13,14,15,
9,10,11,12,13,14,15,
10,11,12,13,14,15,
11,12,13,14,15,
12,13,14,15,
13,14,15,
14,15,
15};

__device__ inline unsigned short f2bf_rne(float x) {
    unsigned u = __float_as_uint(x);
    u += 0x7fff + ((u >> 16) & 1);
    return (unsigned short)(u >> 16);
}
__device__ inline float bf2f(unsigned short h) {
    return __uint_as_float(((unsigned)h) << 16);
}
__device__ inline f32x4 mfma1(bf16x8 a, bf16x8 b, f32x4 acc) {
    return __builtin_amdgcn_mfma_f32_16x16x32_bf16(a, b, acc, 0, 0, 0);
}

// Device-scope grid barrier: one arrival per block on a single monotone
// counter; bounded spin (no hang even if co-residency were violated).
__device__ inline void grid_barrier(unsigned* __restrict__ bar, unsigned target) {
    __threadfence();              // release this block's global writes (agent scope)
    __syncthreads();
    if (threadIdx.x == 0) {
        __hip_atomic_fetch_add(bar, 1u, __ATOMIC_ACQ_REL, __HIP_MEMORY_SCOPE_AGENT);
        for (unsigned it = 0; it < (1u << 18); ++it) {
            if (__hip_atomic_load(bar, __ATOMIC_ACQUIRE, __HIP_MEMORY_SCOPE_AGENT) >= target)
                break;
            __builtin_amdgcn_s_sleep(2);
        }
    }
    __syncthreads();
    __threadfence();              // acquire side: invalidate stale cached lines
}

// row-major features
__device__ inline void feat40(const float* __restrict__ x, int q4,
                              unsigned short* __restrict__ dst) {
    #pragma unroll
    for (int g = 0; g < 10; ++g) {
        short4v s;
        #pragma unroll
        for (int e = 0; e < 4; ++e) {
            const int D = q4 * 40 + g * 4 + e;
            float f;
            if (D == 0)       f = 1.f;
            else if (D < 17)  f = x[D-1] * 0.5f;
            else if (D < 33)  { float a = x[D-17]; f = a * a * 0.17677669529663687f; }
            else if (D < 153) { int p = D - 33; f = x[c_iu[p]] * x[c_ju[p]] * 0.25f; }
            else              f = 0.f;
            s[e] = (short)f2bf_rne(f);
        }
        *(short4v*)(dst + q4 * 40 + g * 4) = s;
    }
}

// transposed features
__device__ inline void feat40T(const float* __restrict__ x, int q4, int r,
                               unsigned short (*KT)[72]) {
    #pragma unroll
    for (int g = 0; g < 10; ++g) {
        #pragma unroll
        for (int e = 0; e < 4; ++e) {
            const int D = q4 * 40 + g * 4 + e;
            float f;
            if (D == 0)       f = 1.f;
            else if (D < 17)  f = x[D-1] * 0.5f;
            else if (D < 33)  { float a = x[D-17]; f = a * a * 0.17677669529663687f; }
            else if (D < 153) { int p = D - 33; f = x[c_iu[p]] * x[c_ju[p]] * 0.25f; }
            else              f = 0.f;
            KT[D][r] = f2bf_rne(f);
        }
    }
}

__global__ void barinit(unsigned* __restrict__ bar) {
    if (threadIdx.x == 0) *bar = 0u;
}

// ============================================================================
// FUSED persistent kernel: all 5 phases, plain launch (graph-capture safe),
// manual device-scope grid barrier between phases.
// grid = 256 blocks x 512 threads; LDS 116736 B -> 1 block/CU -> all 256
// blocks co-resident on 256 CUs.
// ============================================================================
__global__ __launch_bounds__(512)
void fused(const float* __restrict__ hs, const float* __restrict__ Wq,
           const float* __restrict__ Wk, const float* __restrict__ Wv,
           const float* __restrict__ Wo,
           short* __restrict__ hsh, short* __restrict__ Wch, short* __restrict__ Woh,
           short* __restrict__ Cp, short* __restrict__ S, float* __restrict__ Z,
           short* __restrict__ Y, float* __restrict__ out,
           unsigned* __restrict__ bar) {
    __shared__ __align__(16) char smem[116736];
    const int tid = threadIdx.x;
    const int bid = blockIdx.x;

    // ---------------- phase 0: preconv (f32 -> bf16), 7 strided items/thread --
    #pragma unroll
    for (int it = 0; it < 7; ++it) {
        const int i4 = it * 131072 + bid * 512 + tid;   // 7*131072 == 917504 exactly
        const float* src; short* dh; size_t off4;
        if (i4 < 262144)      { src = hs; dh = hsh;          off4 = i4; }
        else if (i4 < 327680) { src = Wq; dh = Wch;          off4 = i4 - 262144; }
        else if (i4 < 393216) { src = Wk; dh = Wch + 262144; off4 = i4 - 327680; }
        else if (i4 < 655360) { src = Wv; dh = Wch + 524288; off4 = i4 - 393216; }
        else                  { src = Wo; dh = Woh;          off4 = i4 - 655360; }
        float4 v = *(const float4*)(src + off4 * 4);
        float vv[4] = {v.x, v.y, v.z, v.w};
        short4v sh;
        #pragma unroll
        for (int e = 0; e < 4; ++e) sh[e] = (short)f2bf_rne(vv[e]);
        *(short4v*)(dh + off4 * 4) = sh;
    }
    grid_barrier(bar, 256u * 1u);

    // ---------------- phase 1: gemm_proj  Cp = hsh @ Wch^T  (64x96 tile) ------
    {
        short (*sA)[2][64][72] = (short(*)[2][64][72])(smem);            // 36864 B
        short (*sB)[2][96][72] = (short(*)[2][96][72])(smem + 36864);    // 55296 B
        float (*sRed)[24]      = (float(*)[24])(smem + 92160);           // 24576 B
        const int half = tid >> 8;
        const int ht = tid & 255;
        const int bm = (bid >> 4) * 64, bn = (bid & 15) * 96;
        const int lane = ht & 63, w2 = ht >> 6;
        const int wm = (w2 & 1) * 32, wn = (w2 >> 1) * 48;
        const int srA = ht >> 2, skA = (ht & 3) * 16;
        const int srB = ht >> 1, skB = (ht & 1) * 32;
        const int fm = lane & 15, fk = (lane >> 4) * 8;
        const int kbase = half * 512;
        f32x4 acc[2][3] = {};
        const short* pA = hsh + (size_t)(bm + srA) * 1024 + kbase + skA;
        const short* pB = Wch + (size_t)(bn + (srB < 96 ? srB : 0)) * 1024 + kbase + skB;
        bf16x8 va0 = *(const bf16x8*)pA, va1 = *(const bf16x8*)(pA + 8);
        bf16x8 vb0, vb1, vb2, vb3;
        if (ht < 192) {
            vb0 = *(const bf16x8*)pB;        vb1 = *(const bf16x8*)(pB + 8);
            vb2 = *(const bf16x8*)(pB + 16); vb3 = *(const bf16x8*)(pB + 24);
        }
        *(bf16x8*)&sA[half][0][srA][skA]     = va0;
        *(bf16x8*)&sA[half][0][srA][skA + 8] = va1;
        if (ht < 192) {
            *(bf16x8*)&sB[half][0][srB][skB]      = vb0;
            *(bf16x8*)&sB[half][0][srB][skB + 8]  = vb1;
            *(bf16x8*)&sB[half][0][srB][skB + 16] = vb2;
            *(bf16x8*)&sB[half][0][srB][skB + 24] = vb3;
        }
        va0 = *(const bf16x8*)(pA + 64); va1 = *(const bf16x8*)(pA + 72);
        if (ht < 192) {
            vb0 = *(const bf16x8*)(pB + 64); vb1 = *(const bf16x8*)(pB + 72);
            vb2 = *(const bf16x8*)(pB + 80); vb3 = *(const bf16x8*)(pB + 88);
        }
        __syncthreads();
        for (int k0 = 0; k0 < 512; k0 += 64) {
            const int bb = (k0 >> 6) & 1;
            bf16x8 a[2][2], bfr[2][3];
            #pragma unroll
            for (int ks = 0; ks < 2; ++ks) {
                #pragma unroll
                for (int i = 0; i < 2; ++i)
                    a[ks][i] = *(const bf16x8*)&sA[half][bb][wm + i*16 + fm][ks*32 + fk];
                #pragma unroll
                for (int j = 0; j < 3; ++j)
                    bfr[ks][j] = *(const bf16x8*)&sB[half][bb][wn + j*16 + fm][ks*32 + fk];
            }
            if (k0 + 64 < 512) {
                *(bf16x8*)&sA[half][bb^1][srA][skA]     = va0;
                *(bf16x8*)&sA[half][bb^1][srA][skA + 8] = va1;
                if (ht < 192) {
                    *(bf16x8*)&sB[half][bb^1][srB][skB]      = vb0;
                    *(bf16x8*)&sB[half][bb^1][srB][skB + 8]  = vb1;
                    *(bf16x8*)&sB[half][bb^1][srB][skB + 16] = vb2;
                    *(bf16x8*)&sB[half][bb^1][srB][skB + 24] = vb3;
                }
            }
            if (k0 + 128 < 512) {
                va0 = *(const bf16x8*)(pA + k0 + 128); va1 = *(const bf16x8*)(pA + k0 + 136);
                if (ht < 192) {
                    vb0 = *(const bf16x8*)(pB + k0 + 128); vb1 = *(const bf16x8*)(pB + k0 + 136);
                    vb2 = *(const bf16x8*)(pB + k0 + 144); vb3 = *(const bf16x8*)(pB + k0 + 152);
                }
            }
            #pragma unroll
            for (int ks = 0; ks < 2; ++ks)
                #pragma unroll
                for (int j = 0; j < 3; ++j)
                    #pragma unroll
                    for (int i = 0; i < 2; ++i)
                        acc[i][j] = mfma1(a[ks][i], bfr[ks][j], acc[i][j]);
            __syncthreads();
        }
        __syncthreads();
        if (half == 1) {
            #pragma unroll
            for (int i = 0; i < 2; ++i)
                #pragma unroll
                for (int j = 0; j < 3; ++j)
                    *(f32x4*)&sRed[ht][(i*3 + j) * 4] = acc[i][j];
        }
        __syncthreads();
        if (half == 0) {
            const int crow0 = (lane >> 4) * 4, ccol = lane & 15;
            #pragma unroll
            for (int i = 0; i < 2; ++i)
                #pragma unroll
                for (int j = 0; j < 3; ++j) {
                    f32x4 o = acc[i][j];
                    f32x4 p = *(const f32x4*)&sRed[ht][(i*3 + j) * 4];
                    #pragma unroll
                    for (int r = 0; r < 4; ++r)
                        Cp[(size_t)(bm + wm + i*16 + crow0 + r) * 1536 + bn + wn + j*16 + ccol] =
                            (short)f2bf_rne(o[r] + p[r]);
                }
        }
    }
    grid_barrier(bar, 256u * 2u);

    // ---------------- phase 2: chunk_state (tid<256 active) -------------------
    {
        float (*sKP)[17]          = (float(*)[17])(smem);                       // 4352 B
        unsigned short (*sKT)[72] = (unsigned short(*)[72])(smem + 4352);       // 23040 B
        unsigned short (*sVT)[72] = (unsigned short(*)[72])(smem + 27392);      // 9216 B
        const int bh = bid >> 3, c = bid & 7;
        const int b = bh >> 4, h = bh & 15;
        const int lane = tid & 63, w = tid >> 6;
        const int wm = (w & 1) * 32, wn = ((w >> 1) & 1) * 80;
        const int fm = lane & 15, fk = (lane >> 4) * 8;
        const int r = (tid & 255) >> 2, q4 = tid & 3;
        const size_t rowbase = (size_t)(b*T + c*CH + r) * 1536;
        if (tid < 256) {
            {
                short4v kv = *(const short4v*)(Cp + rowbase + 256 + h*16 + q4*4);
                float4 kf;
                kf.x = bf2f((unsigned short)kv[0]); kf.y = bf2f((unsigned short)kv[1]);
                kf.z = bf2f((unsigned short)kv[2]); kf.w = bf2f((unsigned short)kv[3]);
                *(float4*)&sKP[r][q4*4] = kf;
            }
            {
                const short* vsrc = Cp + rowbase + 512 + h*HD + q4*16;
                bf16x8 v0 = *(const bf16x8*)vsrc, v1 = *(const bf16x8*)(vsrc + 8);
                #pragma unroll
                for (int e = 0; e < 8; ++e) {
                    sVT[q4*16 + e][r]     = (unsigned short)v0[e];
                    sVT[q4*16 + 8 + e][r] = (unsigned short)v1[e];
                }
            }
        }
        __syncthreads();
        if (tid < 256) feat40T(sKP[r], q4, r, sKT);
        __syncthreads();
        if (tid < 256) {
            if (tid < DP) {
                float zz = 0.f;
                #pragma unroll
                for (int blk = 0; blk < 8; ++blk) {
                    bf16x8 v = *(const bf16x8*)&sKT[tid][blk*8];
                    #pragma unroll
                    for (int e = 0; e < 8; ++e) zz += bf2f((unsigned short)v[e]);
                }
                Z[((size_t)(bh*NC + c)) * DP + tid] = zz;
            }
            f32x4 acc[2][5] = {};
            #pragma unroll
            for (int k0 = 0; k0 < 64; k0 += 32) {
                bf16x8 a[2];
                #pragma unroll
                for (int i = 0; i < 2; ++i)
                    a[i] = *(const bf16x8*)&sVT[wm + i*16 + fm][k0 + fk];
                #pragma unroll
                for (int j = 0; j < 5; ++j) {
                    bf16x8 bv = *(const bf16x8*)&sKT[wn + j*16 + fm][k0 + fk];
                    #pragma unroll
                    for (int i = 0; i < 2; ++i)
                        acc[i][j] = mfma1(a[i], bv, acc[i][j]);
                }
            }
            const int crow0 = (lane >> 4) * 4, ccol = lane & 15;
            short* Sb = S + ((size_t)(bh*NC + c)) * CH * DP;
            #pragma unroll
            for (int i = 0; i < 2; ++i)
                #pragma unroll
                for (int j = 0; j < 5; ++j)
                    #pragma unroll
                    for (int rr = 0; rr < 4; ++rr)
                        Sb[(size_t)(wm + i*16 + crow0 + rr) * DP + wn + j*16 + ccol] =
                            (short)f2bf_rne(acc[i][j][rr]);
        }
    }
    grid_barrier(bar, 256u * 3u);

    // ---------------- phase 3: chunk_out (tid<256 active, barriers hoisted) ---
    {
        float (*sQP)[17]          = (float(*)[17])(smem);                       // 4352
        float (*sKP)[17]          = (float(*)[17])(smem + 4352);                // 4352
        unsigned short (*sQf)[168]= (unsigned short(*)[168])(smem + 8704);      // 21504
        unsigned short (*sKf)[168]= (unsigned short(*)[168])(smem + 30208);     // 21504
        unsigned short (*sPb)[168]= (unsigned short(*)[168])(smem + 51712);     // 21504
        unsigned short (*sAb)[72] = (unsigned short(*)[72])(smem + 73216);      // 9216
        unsigned short (*sVT)[72] = (unsigned short(*)[72])(smem + 82432);      // 9216
        float* sZp  = (float*)(smem + 91648);                                   // 640
        float* sDen = (float*)(smem + 92288);                                   // 256
        const int bh = bid >> 3, c = bid & 7;
        const int b = bh >> 4, h = bh & 15;
        const int lane = tid & 63, w = tid >> 6;
        const int wm = (w & 1) * 32, wn = ((w >> 1) & 1) * 32;
        const int fm = lane & 15, fk = (lane >> 4) * 8;
        const int r = (tid & 255) >> 2, q4 = tid & 3;
        const int crow0 = (lane >> 4) * 4, ccol = lane & 15;
        const size_t rowbase = (size_t)(b*T + c*CH + r) * 1536;
        f32x4 accA[2][2] = {};
        f32x4 accI[2][2] = {};
        if (tid < 256) {
            {
                short4v qv = *(const short4v*)(Cp + rowbase + h*16 + q4*4);
                short4v kv = *(const short4v*)(Cp + rowbase + 256 + h*16 + q4*4);
                float4 qf, kf;
                qf.x = bf2f((unsigned short)qv[0]); qf.y = bf2f((unsigned short)qv[1]);
                qf.z = bf2f((unsigned short)qv[2]); qf.w = bf2f((unsigned short)qv[3]);
                kf.x = bf2f((unsigned short)kv[0]); kf.y = bf2f((unsigned short)kv[1]);
                kf.z = bf2f((unsigned short)kv[2]); kf.w = bf2f((unsigned short)kv[3]);
                *(float4*)&sQP[r][q4*4] = qf;
                *(float4*)&sKP[r][q4*4] = kf;
            }
            {
                const short* vsrc = Cp + rowbase + 512 + h*HD + q4*16;
                bf16x8 v0 = *(const bf16x8*)vsrc, v1 = *(const bf16x8*)(vsrc + 8);
                #pragma unroll
                for (int e = 0; e < 8; ++e) {
                    sVT[q4*16 + e][r]     = (unsigned short)v0[e];
                    sVT[q4*16 + 8 + e][r] = (unsigned short)v1[e];
                }
            }
            if (tid < DP) {
                float zz = 0.f;
                for (int cc = 0; cc < c; ++cc) zz += Z[((size_t)(bh*NC + cc)) * DP + tid];
                sZp[tid] = zz;
            }
        }
        __syncthreads();
        if (tid < 256) {
            feat40(sQP[r], q4, (unsigned short*)sQf[r]);
            feat40(sKP[r], q4, (unsigned short*)sKf[r]);
            for (int e = tid; e < 1280; e += 256) {
                const int d = e / 20, D8 = (e % 20) * 8;
                float a[8] = {};
                for (int cc = 0; cc < c; ++cc) {
                    bf16x8 s = *(const bf16x8*)(S + (((size_t)(bh*NC + cc)) * CH + d) * DP + D8);
                    #pragma unroll
                    for (int e2 = 0; e2 < 8; ++e2) a[e2] += bf2f((unsigned short)s[e2]);
                }
                bf16x8 o;
                #pragma unroll
                for (int e2 = 0; e2 < 8; ++e2) o[e2] = (short)f2bf_rne(a[e2]);
                *(bf16x8*)&sPb[d][D8] = o;
            }
        }
        __syncthreads();
        if (tid < 256) {
            for (int k0 = 0; k0 < DP; k0 += 32) {
                bf16x8 qv[2];
                #pragma unroll
                for (int i = 0; i < 2; ++i)
                    qv[i] = *(const bf16x8*)&sQf[wm + i*16 + fm][k0 + fk];
                #pragma unroll
                for (int j = 0; j < 2; ++j) {
                    bf16x8 kv = *(const bf16x8*)&sKf[wn + j*16 + fm][k0 + fk];
                    bf16x8 pv = *(const bf16x8*)&sPb[wn + j*16 + fm][k0 + fk];
                    #pragma unroll
                    for (int i = 0; i < 2; ++i) {
                        accA[i][j] = mfma1(qv[i], kv, accA[i][j]);
                        accI[i][j] = mfma1(qv[i], pv, accI[i][j]);
                    }
                }
            }
            {
                float dp = 0.f;
                #pragma unroll
                for (int g = 0; g < 5; ++g) {
                    bf16x8 v = *(const bf16x8*)&sQf[r][q4*40 + g*8];
                    #pragma unroll
                    for (int e = 0; e < 8; ++e)
                        dp += bf2f((unsigned short)v[e]) * sZp[q4*40 + g*8 + e];
                }
                dp += __shfl_xor(dp, 1);
                dp += __shfl_xor(dp, 2);
                if (q4 == 0) sDen[r] = dp;
            }
            #pragma unroll
            for (int i = 0; i < 2; ++i)
                #pragma unroll
                for (int j = 0; j < 2; ++j)
                    #pragma unroll
                    for (int rr = 0; rr < 4; ++rr) {
                        const int t_ = wm + i*16 + crow0 + rr, s_ = wn + j*16 + ccol;
                        sAb[t_][s_] = (s_ <= t_) ? f2bf_rne(accA[i][j][rr]) : 0;
                    }
        }
        __syncthreads();
        if (tid < 256) {
            float rs = 0.f;
            bf16x8 v0 = *(const bf16x8*)&sAb[r][q4*16];
            bf16x8 v1 = *(const bf16x8*)&sAb[r][q4*16 + 8];
            #pragma unroll
            for (int e = 0; e < 8; ++e)
                rs += bf2f((unsigned short)v0[e]) + bf2f((unsigned short)v1[e]);
            rs += __shfl_xor(rs, 1);
            rs += __shfl_xor(rs, 2);
            if (q4 == 0) sDen[r] += rs;
        }
        __syncthreads();
        if (tid < 256) {
            #pragma unroll
            for (int k0 = 0; k0 < 64; k0 += 32) {
                bf16x8 a[2];
                #pragma unroll
                for (int i = 0; i < 2; ++i)
                    a[i] = *(const bf16x8*)&sAb[wm + i*16 + fm][k0 + fk];
                #pragma unroll
                for (int j = 0; j < 2; ++j) {
                    bf16x8 bv = *(const bf16x8*)&sVT[wn + j*16 + fm][k0 + fk];
                    #pragma unroll
                    for (int i = 0; i < 2; ++i)
                        accI[i][j] = mfma1(a[i], bv, accI[i][j]);
                }
            }
            #pragma unroll
            for (int i = 0; i < 2; ++i)
                #pragma unroll
                for (int rr = 0; rr < 4; ++rr) {
                    const int t_ = wm + i*16 + crow0 + rr;
                    const float inv = 1.f / (sDen[t_] + 1e-12f);
                    const size_t grow = (size_t)(b*T + c*CH + t_) * 1024 + h*HD;
                    #pragma unroll
                    for (int j = 0; j < 2; ++j)
                        Y[grow + wn + j*16 + ccol] = (short)f2bf_rne(accI[i][j][rr] * inv);
                }
        }
    }
    grid_barrier(bar, 256u * 4u);

    // ---------------- phase 4: gemm_out  out = Y @ Woh^T  (64x64 tile) --------
    {
        short (*sA)[2][64][72] = (short(*)[2][64][72])(smem);            // 36864 B
        short (*sB)[2][64][72] = (short(*)[2][64][72])(smem + 36864);    // 36864 B
        float (*sRed)[16]      = (float(*)[16])(smem + 73728);           // 16384 B
        const int half = tid >> 8;
        const int ht = tid & 255;
        const int bm = (bid >> 4) * 64, bn = (bid & 15) * 64;
        const int lane = ht & 63, w2 = ht >> 6;
        const int wm = (w2 & 1) * 32, wn = (w2 >> 1) * 32;
        const int srow = ht >> 2, skq = (ht & 3) * 16;
        const int fm = lane & 15, fk = (lane >> 4) * 8;
        const int kbase = half * 512;
        f32x4 acc[2][2] = {};
        const short* pA = Y   + (size_t)(bm + srow) * 1024 + kbase + skq;
        const short* pB = Woh + (size_t)(bn + srow) * 1024 + kbase + skq;
        bf16x8 va0 = *(const bf16x8*)pA, va1 = *(const bf16x8*)(pA + 8);
        bf16x8 vb0 = *(const bf16x8*)pB, vb1 = *(const bf16x8*)(pB + 8);
        *(bf16x8*)&sA[half][0][srow][skq]     = va0;
        *(bf16x8*)&sA[half][0][srow][skq + 8] = va1;
        *(bf16x8*)&sB[half][0][srow][skq]     = vb0;
        *(bf16x8*)&sB[half][0][srow][skq + 8] = vb1;
        va0 = *(const bf16x8*)(pA + 64); va1 = *(const bf16x8*)(pA + 72);
        vb0 = *(const bf16x8*)(pB + 64); vb1 = *(const bf16x8*)(pB + 72);
        __syncthreads();
        for (int k0 = 0; k0 < 512; k0 += 64) {
            const int bb = (k0 >> 6) & 1;
            bf16x8 a[2][2], b2[2][2];
            #pragma unroll
            for (int ks = 0; ks < 2; ++ks)
                #pragma unroll
                for (int i = 0; i < 2; ++i) {
                    a[ks][i]  = *(const bf16x8*)&sA[half][bb][wm + i*16 + fm][ks*32 + fk];
                    b2[ks][i] = *(const bf16x8*)&sB[half][bb][wn + i*16 + fm][ks*32 + fk];
                }
            if (k0 + 64 < 512) {
                *(bf16x8*)&sA[half][bb^1][srow][skq]     = va0;
                *(bf16x8*)&sA[half][bb^1][srow][skq + 8] = va1;
                *(bf16x8*)&sB[half][bb^1][srow][skq]     = vb0;
                *(bf16x8*)&sB[half][bb^1][srow][skq + 8] = vb1;
            }
            if (k0 + 128 < 512) {
                va0 = *(const bf16x8*)(pA + k0 + 128); va1 = *(const bf16x8*)(pA + k0 + 136);
                vb0 = *(const bf16x8*)(pB + k0 + 128); vb1 = *(const bf16x8*)(pB + k0 + 136);
            }
            #pragma unroll
            for (int ks = 0; ks < 2; ++ks)
                #pragma unroll
                for (int i = 0; i < 2; ++i)
                    #pragma unroll
                    for (int j = 0; j < 2; ++j)
                        acc[i][j] = mfma1(a[ks][i], b2[ks][j], acc[i][j]);
            __syncthreads();
        }
        __syncthreads();
        if (half == 1) {
            #pragma unroll
            for (int i = 0; i < 2; ++i)
                #pragma unroll
                for (int j = 0; j < 2; ++j)
                    *(f32x4*)&sRed[ht][(i*2 + j) * 4] = acc[i][j];
        }
        __syncthreads();
        if (half == 0) {
            const int crow0 = (lane >> 4) * 4, ccol = lane & 15;
            #pragma unroll
            for (int i = 0; i < 2; ++i)
                #pragma unroll
                for (int j = 0; j < 2; ++j) {
                    f32x4 p = *(const f32x4*)&sRed[ht][(i*2 + j) * 4];
                    #pragma unroll
                    for (int r = 0; r < 4; ++r)
                        out[(size_t)(bm + wm + i*16 + crow0 + r) * 1024 + bn + wn + j*16 + ccol] =
                            acc[i][j][r] + p[r];
                }
        }
    }
}

extern "C" void kernel_launch(void* const* d_in, const int* in_sizes, int n_in,
                              void* d_out, int out_size, void* d_ws, size_t ws_size,
                              hipStream_t stream) {
    const float* hs = (const float*)d_in[0];
    const float* Wq = (const float*)d_in[1];
    const float* Wk = (const float*)d_in[2];
    const float* Wv = (const float*)d_in[3];
    const float* Wo = (const float*)d_in[4];
    float* out = (float*)d_out;

    char* p = (char*)d_ws;
    short* Cp  = (short*)p; p += (size_t)1024*1536*2;
    short* hsh = (short*)p; p += (size_t)1048576*2;
    short* Wch = (short*)p; p += (size_t)1536*1024*2;
    short* Woh = (short*)p; p += (size_t)1048576*2;
    short* S   = (short*)p; p += (size_t)32*NC*CH*DP*2;
    float* Z   = (float*)p; p += (size_t)32*NC*DP*4;
    short* Y   = (short*)p; p += (size_t)1048576*2;
    unsigned* bar = (unsigned*)p; p += 256;

    barinit<<<dim3(1), dim3(64), 0, stream>>>(bar);
    fused<<<dim3(256), dim3(512), 0, stream>>>(hs, Wq, Wk, Wv, Wo,
                                               hsh, Wch, Woh, Cp, S, Z, Y, out, bar);
}

// Round 3
// 182.411 us; speedup vs baseline: 2.6921x; 2.6921x over previous
//
#include <hip/hip_runtime.h>

#define T 512
#define B 2
#define NH 16
#define FD 16
#define HD 64
#define DP 160
#define CH 64
#define NC 8

typedef __attribute__((ext_vector_type(4))) short short4v;
typedef __attribute__((ext_vector_type(8))) short bf16x8;
typedef __attribute__((ext_vector_type(4))) float f32x4;

__constant__ unsigned char c_iu[120] = {
0,0,0,0,0,0,0,0,0,0,0,0,0,0,0,
1,1,1,1,1,1,1,1,1,1,1,1,1,1,
2,2,2,2,2,2,2,2,2,2,2,2,2,
3,3,3,3,3,3,3,3,3,3,3,3,
4,4,4,4,4,4,4,4,4,4,4,
5,5,5,5,5,5,5,5,5,5,
6,6,6,6,6,6,6,6,6,
7,7,7,7,7,7,7,7,
8,8,8,8,8,8,8,
9,9,9,9,9,9,
10,10,10,10,10,
11,11,11,11,
12,12,12,
13,13,
14};
__constant__ unsigned char c_ju[120] = {
1,2,3,4,5,6,7,8,9,10,11,12,13,14,15,
2,3,4,5,6,7,8,9,10,11,12,13,14,15,
3,4,5,6,7,8,9,10,11,12,13,14,15,
4,5,6,7,8,9,10,11,12,13,14,15,
5,6,7,8,9,10,11,12,13,14,15,
6,7,8,9,10,11,12,13,14,15,
7,8,9,10,11,12,13,14,15,
8,9,10,11,12,13,14,15,
9,10,11,12,13,14,15,
10,11,12,13,14,15,
11,12,13,14,15,
12,13,14,15,
13,14,15,
14,15,
15};

__device__ inline unsigned short f2bf_rne(float x) {
    unsigned u = __float_as_uint(x);
    u += 0x7fff + ((u >> 16) & 1);
    return (unsigned short)(u >> 16);
}
__device__ inline float bf2f(unsigned short h) {
    return __uint_as_float(((unsigned)h) << 16);
}
__device__ inline f32x4 mfma1(bf16x8 a, bf16x8 b, f32x4 acc) {
    return __builtin_amdgcn_mfma_f32_16x16x32_bf16(a, b, acc, 0, 0, 0);
}

// Device-scope grid barrier with MINIMAL cache maintenance:
//  - one agent-release fence (single L2 writeback) on arrival, thread 0 only
//  - RELAXED spin loads (no per-iteration buffer_inv!)
//  - one agent-acquire fence (single L2/L1 invalidate) on exit, thread 0 only
// Bounded spin: no hang even if co-residency were violated (wrong answer
// instead, caught by the checker).
__device__ inline void grid_barrier(unsigned* __restrict__ bar, unsigned target) {
    __syncthreads();   // drains each wave's stores to L2 (HIP inserts vmcnt wait)
    if (threadIdx.x == 0) {
        __builtin_amdgcn_fence(__ATOMIC_RELEASE, "agent");   // one buffer_wbl2
        __hip_atomic_fetch_add(bar, 1u, __ATOMIC_RELAXED, __HIP_MEMORY_SCOPE_AGENT);
        unsigned it = 0;
        while (__hip_atomic_load(bar, __ATOMIC_RELAXED, __HIP_MEMORY_SCOPE_AGENT) < target) {
            __builtin_amdgcn_s_sleep(2);
            if (++it > (1u << 20)) break;                    // ~timeout, no hang
        }
        __builtin_amdgcn_fence(__ATOMIC_ACQUIRE, "agent");   // one buffer_inv
    }
    __syncthreads();
}

// row-major features
__device__ inline void feat40(const float* __restrict__ x, int q4,
                              unsigned short* __restrict__ dst) {
    #pragma unroll
    for (int g = 0; g < 10; ++g) {
        short4v s;
        #pragma unroll
        for (int e = 0; e < 4; ++e) {
            const int D = q4 * 40 + g * 4 + e;
            float f;
            if (D == 0)       f = 1.f;
            else if (D < 17)  f = x[D-1] * 0.5f;
            else if (D < 33)  { float a = x[D-17]; f = a * a * 0.17677669529663687f; }
            else if (D < 153) { int p = D - 33; f = x[c_iu[p]] * x[c_ju[p]] * 0.25f; }
            else              f = 0.f;
            s[e] = (short)f2bf_rne(f);
        }
        *(short4v*)(dst + q4 * 40 + g * 4) = s;
    }
}

// transposed features
__device__ inline void feat40T(const float* __restrict__ x, int q4, int r,
                               unsigned short (*KT)[72]) {
    #pragma unroll
    for (int g = 0; g < 10; ++g) {
        #pragma unroll
        for (int e = 0; e < 4; ++e) {
            const int D = q4 * 40 + g * 4 + e;
            float f;
            if (D == 0)       f = 1.f;
            else if (D < 17)  f = x[D-1] * 0.5f;
            else if (D < 33)  { float a = x[D-17]; f = a * a * 0.17677669529663687f; }
            else if (D < 153) { int p = D - 33; f = x[c_iu[p]] * x[c_ju[p]] * 0.25f; }
            else              f = 0.f;
            KT[D][r] = f2bf_rne(f);
        }
    }
}

__global__ void barinit(unsigned* __restrict__ bar) {
    if (threadIdx.x == 0) *bar = 0u;
}

// ============================================================================
// FUSED persistent kernel: all 5 phases, plain launch (graph-capture safe),
// manual device-scope grid barrier between phases.
// grid = 256 blocks x 512 threads; LDS 116736 B -> 1 block/CU -> all 256
// blocks co-resident on 256 CUs.
// ============================================================================
__global__ __launch_bounds__(512)
void fused(const float* __restrict__ hs, const float* __restrict__ Wq,
           const float* __restrict__ Wk, const float* __restrict__ Wv,
           const float* __restrict__ Wo,
           short* __restrict__ hsh, short* __restrict__ Wch, short* __restrict__ Woh,
           short* __restrict__ Cp, short* __restrict__ S, float* __restrict__ Z,
           short* __restrict__ Y, float* __restrict__ out,
           unsigned* __restrict__ bar) {
    __shared__ __align__(16) char smem[116736];
    const int tid = threadIdx.x;
    const int bid = blockIdx.x;

    // ---------------- phase 0: preconv (f32 -> bf16), 7 strided items/thread --
    #pragma unroll
    for (int it = 0; it < 7; ++it) {
        const int i4 = it * 131072 + bid * 512 + tid;   // 7*131072 == 917504 exactly
        const float* src; short* dh; size_t off4;
        if (i4 < 262144)      { src = hs; dh = hsh;          off4 = i4; }
        else if (i4 < 327680) { src = Wq; dh = Wch;          off4 = i4 - 262144; }
        else if (i4 < 393216) { src = Wk; dh = Wch + 262144; off4 = i4 - 327680; }
        else if (i4 < 655360) { src = Wv; dh = Wch + 524288; off4 = i4 - 393216; }
        else                  { src = Wo; dh = Woh;          off4 = i4 - 655360; }
        float4 v = *(const float4*)(src + off4 * 4);
        float vv[4] = {v.x, v.y, v.z, v.w};
        short4v sh;
        #pragma unroll
        for (int e = 0; e < 4; ++e) sh[e] = (short)f2bf_rne(vv[e]);
        *(short4v*)(dh + off4 * 4) = sh;
    }
    grid_barrier(bar, 256u * 1u);

    // ---------------- phase 1: gemm_proj  Cp = hsh @ Wch^T  (64x96 tile) ------
    {
        short (*sA)[2][64][72] = (short(*)[2][64][72])(smem);            // 36864 B
        short (*sB)[2][96][72] = (short(*)[2][96][72])(smem + 36864);    // 55296 B
        float (*sRed)[24]      = (float(*)[24])(smem + 92160);           // 24576 B
        const int half = tid >> 8;
        const int ht = tid & 255;
        const int bm = (bid >> 4) * 64, bn = (bid & 15) * 96;
        const int lane = ht & 63, w2 = ht >> 6;
        const int wm = (w2 & 1) * 32, wn = (w2 >> 1) * 48;
        const int srA = ht >> 2, skA = (ht & 3) * 16;
        const int srB = ht >> 1, skB = (ht & 1) * 32;
        const int fm = lane & 15, fk = (lane >> 4) * 8;
        const int kbase = half * 512;
        f32x4 acc[2][3] = {};
        const short* pA = hsh + (size_t)(bm + srA) * 1024 + kbase + skA;
        const short* pB = Wch + (size_t)(bn + (srB < 96 ? srB : 0)) * 1024 + kbase + skB;
        bf16x8 va0 = *(const bf16x8*)pA, va1 = *(const bf16x8*)(pA + 8);
        bf16x8 vb0, vb1, vb2, vb3;
        if (ht < 192) {
            vb0 = *(const bf16x8*)pB;        vb1 = *(const bf16x8*)(pB + 8);
            vb2 = *(const bf16x8*)(pB + 16); vb3 = *(const bf16x8*)(pB + 24);
        }
        *(bf16x8*)&sA[half][0][srA][skA]     = va0;
        *(bf16x8*)&sA[half][0][srA][skA + 8] = va1;
        if (ht < 192) {
            *(bf16x8*)&sB[half][0][srB][skB]      = vb0;
            *(bf16x8*)&sB[half][0][srB][skB + 8]  = vb1;
            *(bf16x8*)&sB[half][0][srB][skB + 16] = vb2;
            *(bf16x8*)&sB[half][0][srB][skB + 24] = vb3;
        }
        va0 = *(const bf16x8*)(pA + 64); va1 = *(const bf16x8*)(pA + 72);
        if (ht < 192) {
            vb0 = *(const bf16x8*)(pB + 64); vb1 = *(const bf16x8*)(pB + 72);
            vb2 = *(const bf16x8*)(pB + 80); vb3 = *(const bf16x8*)(pB + 88);
        }
        __syncthreads();
        for (int k0 = 0; k0 < 512; k0 += 64) {
            const int bb = (k0 >> 6) & 1;
            bf16x8 a[2][2], bfr[2][3];
            #pragma unroll
            for (int ks = 0; ks < 2; ++ks) {
                #pragma unroll
                for (int i = 0; i < 2; ++i)
                    a[ks][i] = *(const bf16x8*)&sA[half][bb][wm + i*16 + fm][ks*32 + fk];
                #pragma unroll
                for (int j = 0; j < 3; ++j)
                    bfr[ks][j] = *(const bf16x8*)&sB[half][bb][wn + j*16 + fm][ks*32 + fk];
            }
            if (k0 + 64 < 512) {
                *(bf16x8*)&sA[half][bb^1][srA][skA]     = va0;
                *(bf16x8*)&sA[half][bb^1][srA][skA + 8] = va1;
                if (ht < 192) {
                    *(bf16x8*)&sB[half][bb^1][srB][skB]      = vb0;
                    *(bf16x8*)&sB[half][bb^1][srB][skB + 8]  = vb1;
                    *(bf16x8*)&sB[half][bb^1][srB][skB + 16] = vb2;
                    *(bf16x8*)&sB[half][bb^1][srB][skB + 24] = vb3;
                }
            }
            if (k0 + 128 < 512) {
                va0 = *(const bf16x8*)(pA + k0 + 128); va1 = *(const bf16x8*)(pA + k0 + 136);
                if (ht < 192) {
                    vb0 = *(const bf16x8*)(pB + k0 + 128); vb1 = *(const bf16x8*)(pB + k0 + 136);
                    vb2 = *(const bf16x8*)(pB + k0 + 144); vb3 = *(const bf16x8*)(pB + k0 + 152);
                }
            }
            #pragma unroll
            for (int ks = 0; ks < 2; ++ks)
                #pragma unroll
                for (int j = 0; j < 3; ++j)
                    #pragma unroll
                    for (int i = 0; i < 2; ++i)
                        acc[i][j] = mfma1(a[ks][i], bfr[ks][j], acc[i][j]);
            __syncthreads();
        }
        __syncthreads();
        if (half == 1) {
            #pragma unroll
            for (int i = 0; i < 2; ++i)
                #pragma unroll
                for (int j = 0; j < 3; ++j)
                    *(f32x4*)&sRed[ht][(i*3 + j) * 4] = acc[i][j];
        }
        __syncthreads();
        if (half == 0) {
            const int crow0 = (lane >> 4) * 4, ccol = lane & 15;
            #pragma unroll
            for (int i = 0; i < 2; ++i)
                #pragma unroll
                for (int j = 0; j < 3; ++j) {
                    f32x4 o = acc[i][j];
                    f32x4 p = *(const f32x4*)&sRed[ht][(i*3 + j) * 4];
                    #pragma unroll
                    for (int r = 0; r < 4; ++r)
                        Cp[(size_t)(bm + wm + i*16 + crow0 + r) * 1536 + bn + wn + j*16 + ccol] =
                            (short)f2bf_rne(o[r] + p[r]);
                }
        }
    }
    grid_barrier(bar, 256u * 2u);

    // ---------------- phase 2: chunk_state (tid<256 active) -------------------
    {
        float (*sKP)[17]          = (float(*)[17])(smem);                       // 4352 B
        unsigned short (*sKT)[72] = (unsigned short(*)[72])(smem + 4352);       // 23040 B
        unsigned short (*sVT)[72] = (unsigned short(*)[72])(smem + 27392);      // 9216 B
        const int bh = bid >> 3, c = bid & 7;
        const int b = bh >> 4, h = bh & 15;
        const int lane = tid & 63, w = tid >> 6;
        const int wm = (w & 1) * 32, wn = ((w >> 1) & 1) * 80;
        const int fm = lane & 15, fk = (lane >> 4) * 8;
        const int r = (tid & 255) >> 2, q4 = tid & 3;
        const size_t rowbase = (size_t)(b*T + c*CH + r) * 1536;
        if (tid < 256) {
            {
                short4v kv = *(const short4v*)(Cp + rowbase + 256 + h*16 + q4*4);
                float4 kf;
                kf.x = bf2f((unsigned short)kv[0]); kf.y = bf2f((unsigned short)kv[1]);
                kf.z = bf2f((unsigned short)kv[2]); kf.w = bf2f((unsigned short)kv[3]);
                *(float4*)&sKP[r][q4*4] = kf;
            }
            {
                const short* vsrc = Cp + rowbase + 512 + h*HD + q4*16;
                bf16x8 v0 = *(const bf16x8*)vsrc, v1 = *(const bf16x8*)(vsrc + 8);
                #pragma unroll
                for (int e = 0; e < 8; ++e) {
                    sVT[q4*16 + e][r]     = (unsigned short)v0[e];
                    sVT[q4*16 + 8 + e][r] = (unsigned short)v1[e];
                }
            }
        }
        __syncthreads();
        if (tid < 256) feat40T(sKP[r], q4, r, sKT);
        __syncthreads();
        if (tid < 256) {
            if (tid < DP) {
                float zz = 0.f;
                #pragma unroll
                for (int blk = 0; blk < 8; ++blk) {
                    bf16x8 v = *(const bf16x8*)&sKT[tid][blk*8];
                    #pragma unroll
                    for (int e = 0; e < 8; ++e) zz += bf2f((unsigned short)v[e]);
                }
                Z[((size_t)(bh*NC + c)) * DP + tid] = zz;
            }
            f32x4 acc[2][5] = {};
            #pragma unroll
            for (int k0 = 0; k0 < 64; k0 += 32) {
                bf16x8 a[2];
                #pragma unroll
                for (int i = 0; i < 2; ++i)
                    a[i] = *(const bf16x8*)&sVT[wm + i*16 + fm][k0 + fk];
                #pragma unroll
                for (int j = 0; j < 5; ++j) {
                    bf16x8 bv = *(const bf16x8*)&sKT[wn + j*16 + fm][k0 + fk];
                    #pragma unroll
                    for (int i = 0; i < 2; ++i)
                        acc[i][j] = mfma1(a[i], bv, acc[i][j]);
                }
            }
            const int crow0 = (lane >> 4) * 4, ccol = lane & 15;
            short* Sb = S + ((size_t)(bh*NC + c)) * CH * DP;
            #pragma unroll
            for (int i = 0; i < 2; ++i)
                #pragma unroll
                for (int j = 0; j < 5; ++j)
                    #pragma unroll
                    for (int rr = 0; rr < 4; ++rr)
                        Sb[(size_t)(wm + i*16 + crow0 + rr) * DP + wn + j*16 + ccol] =
                            (short)f2bf_rne(acc[i][j][rr]);
        }
    }
    grid_barrier(bar, 256u * 3u);

    // ---------------- phase 3: chunk_out (tid<256 active, barriers hoisted) ---
    {
        float (*sQP)[17]          = (float(*)[17])(smem);                       // 4352
        float (*sKP)[17]          = (float(*)[17])(smem + 4352);                // 4352
        unsigned short (*sQf)[168]= (unsigned short(*)[168])(smem + 8704);      // 21504
        unsigned short (*sKf)[168]= (unsigned short(*)[168])(smem + 30208);     // 21504
        unsigned short (*sPb)[168]= (unsigned short(*)[168])(smem + 51712);     // 21504
        unsigned short (*sAb)[72] = (unsigned short(*)[72])(smem + 73216);      // 9216
        unsigned short (*sVT)[72] = (unsigned short(*)[72])(smem + 82432);      // 9216
        float* sZp  = (float*)(smem + 91648);                                   // 640
        float* sDen = (float*)(smem + 92288);                                   // 256
        const int bh = bid >> 3, c = bid & 7;
        const int b = bh >> 4, h = bh & 15;
        const int lane = tid & 63, w = tid >> 6;
        const int wm = (w & 1) * 32, wn = ((w >> 1) & 1) * 32;
        const int fm = lane & 15, fk = (lane >> 4) * 8;
        const int r = (tid & 255) >> 2, q4 = tid & 3;
        const int crow0 = (lane >> 4) * 4, ccol = lane & 15;
        const size_t rowbase = (size_t)(b*T + c*CH + r) * 1536;
        f32x4 accA[2][2] = {};
        f32x4 accI[2][2] = {};
        if (tid < 256) {
            {
                short4v qv = *(const short4v*)(Cp + rowbase + h*16 + q4*4);
                short4v kv = *(const short4v*)(Cp + rowbase + 256 + h*16 + q4*4);
                float4 qf, kf;
                qf.x = bf2f((unsigned short)qv[0]); qf.y = bf2f((unsigned short)qv[1]);
                qf.z = bf2f((unsigned short)qv[2]); qf.w = bf2f((unsigned short)qv[3]);
                kf.x = bf2f((unsigned short)kv[0]); kf.y = bf2f((unsigned short)kv[1]);
                kf.z = bf2f((unsigned short)kv[2]); kf.w = bf2f((unsigned short)kv[3]);
                *(float4*)&sQP[r][q4*4] = qf;
                *(float4*)&sKP[r][q4*4] = kf;
            }
            {
                const short* vsrc = Cp + rowbase + 512 + h*HD + q4*16;
                bf16x8 v0 = *(const bf16x8*)vsrc, v1 = *(const bf16x8*)(vsrc + 8);
                #pragma unroll
                for (int e = 0; e < 8; ++e) {
                    sVT[q4*16 + e][r]     = (unsigned short)v0[e];
                    sVT[q4*16 + 8 + e][r] = (unsigned short)v1[e];
                }
            }
            if (tid < DP) {
                float zz = 0.f;
                for (int cc = 0; cc < c; ++cc) zz += Z[((size_t)(bh*NC + cc)) * DP + tid];
                sZp[tid] = zz;
            }
        }
        __syncthreads();
        if (tid < 256) {
            feat40(sQP[r], q4, (unsigned short*)sQf[r]);
            feat40(sKP[r], q4, (unsigned short*)sKf[r]);
            for (int e = tid; e < 1280; e += 256) {
                const int d = e / 20, D8 = (e % 20) * 8;
                float a[8] = {};
                for (int cc = 0; cc < c; ++cc) {
                    bf16x8 s = *(const bf16x8*)(S + (((size_t)(bh*NC + cc)) * CH + d) * DP + D8);
                    #pragma unroll
                    for (int e2 = 0; e2 < 8; ++e2) a[e2] += bf2f((unsigned short)s[e2]);
                }
                bf16x8 o;
                #pragma unroll
                for (int e2 = 0; e2 < 8; ++e2) o[e2] = (short)f2bf_rne(a[e2]);
                *(bf16x8*)&sPb[d][D8] = o;
            }
        }
        __syncthreads();
        if (tid < 256) {
            for (int k0 = 0; k0 < DP; k0 += 32) {
                bf16x8 qv[2];
                #pragma unroll
                for (int i = 0; i < 2; ++i)
                    qv[i] = *(const bf16x8*)&sQf[wm + i*16 + fm][k0 + fk];
                #pragma unroll
                for (int j = 0; j < 2; ++j) {
                    bf16x8 kv = *(const bf16x8*)&sKf[wn + j*16 + fm][k0 + fk];
                    bf16x8 pv = *(const bf16x8*)&sPb[wn + j*16 + fm][k0 + fk];
                    #pragma unroll
                    for (int i = 0; i < 2; ++i) {
                        accA[i][j] = mfma1(qv[i], kv, accA[i][j]);
                        accI[i][j] = mfma1(qv[i], pv, accI[i][j]);
                    }
                }
            }
            {
                float dp = 0.f;
                #pragma unroll
                for (int g = 0; g < 5; ++g) {
                    bf16x8 v = *(const bf16x8*)&sQf[r][q4*40 + g*8];
                    #pragma unroll
                    for (int e = 0; e < 8; ++e)
                        dp += bf2f((unsigned short)v[e]) * sZp[q4*40 + g*8 + e];
                }
                dp += __shfl_xor(dp, 1);
                dp += __shfl_xor(dp, 2);
                if (q4 == 0) sDen[r] = dp;
            }
            #pragma unroll
            for (int i = 0; i < 2; ++i)
                #pragma unroll
                for (int j = 0; j < 2; ++j)
                    #pragma unroll
                    for (int rr = 0; rr < 4; ++rr) {
                        const int t_ = wm + i*16 + crow0 + rr, s_ = wn + j*16 + ccol;
                        sAb[t_][s_] = (s_ <= t_) ? f2bf_rne(accA[i][j][rr]) : 0;
                    }
        }
        __syncthreads();
        if (tid < 256) {
            float rs = 0.f;
            bf16x8 v0 = *(const bf16x8*)&sAb[r][q4*16];
            bf16x8 v1 = *(const bf16x8*)&sAb[r][q4*16 + 8];
            #pragma unroll
            for (int e = 0; e < 8; ++e)
                rs += bf2f((unsigned short)v0[e]) + bf2f((unsigned short)v1[e]);
            rs += __shfl_xor(rs, 1);
            rs += __shfl_xor(rs, 2);
            if (q4 == 0) sDen[r] += rs;
        }
        __syncthreads();
        if (tid < 256) {
            #pragma unroll
            for (int k0 = 0; k0 < 64; k0 += 32) {
                bf16x8 a[2];
                #pragma unroll
                for (int i = 0; i < 2; ++i)
                    a[i] = *(const bf16x8*)&sAb[wm + i*16 + fm][k0 + fk];
                #pragma unroll
                for (int j = 0; j < 2; ++j) {
                    bf16x8 bv = *(const bf16x8*)&sVT[wn + j*16 + fm][k0 + fk];
                    #pragma unroll
                    for (int i = 0; i < 2; ++i)
                        accI[i][j] = mfma1(a[i], bv, accI[i][j]);
                }
            }
            #pragma unroll
            for (int i = 0; i < 2; ++i)
                #pragma unroll
                for (int rr = 0; rr < 4; ++rr) {
                    const int t_ = wm + i*16 + crow0 + rr;
                    const float inv = 1.f / (sDen[t_] + 1e-12f);
                    const size_t grow = (size_t)(b*T + c*CH + t_) * 1024 + h*HD;
                    #pragma unroll
                    for (int j = 0; j < 2; ++j)
                        Y[grow + wn + j*16 + ccol] = (short)f2bf_rne(accI[i][j][rr] * inv);
                }
        }
    }
    grid_barrier(bar, 256u * 4u);

    // ---------------- phase 4: gemm_out  out = Y @ Woh^T  (64x64 tile) --------
    {
        short (*sA)[2][64][72] = (short(*)[2][64][72])(smem);            // 36864 B
        short (*sB)[2][64][72] = (short(*)[2][64][72])(smem + 36864);    // 36864 B
        float (*sRed)[16]      = (float(*)[16])(smem + 73728);           // 16384 B
        const int half = tid >> 8;
        const int ht = tid & 255;
        const int bm = (bid >> 4) * 64, bn = (bid & 15) * 64;
        const int lane = ht & 63, w2 = ht >> 6;
        const int wm = (w2 & 1) * 32, wn = (w2 >> 1) * 32;
        const int srow = ht >> 2, skq = (ht & 3) * 16;
        const int fm = lane & 15, fk = (lane >> 4) * 8;
        const int kbase = half * 512;
        f32x4 acc[2][2] = {};
        const short* pA = Y   + (size_t)(bm + srow) * 1024 + kbase + skq;
        const short* pB = Woh + (size_t)(bn + srow) * 1024 + kbase + skq;
        bf16x8 va0 = *(const bf16x8*)pA, va1 = *(const bf16x8*)(pA + 8);
        bf16x8 vb0 = *(const bf16x8*)pB, vb1 = *(const bf16x8*)(pB + 8);
        *(bf16x8*)&sA[half][0][srow][skq]     = va0;
        *(bf16x8*)&sA[half][0][srow][skq + 8] = va1;
        *(bf16x8*)&sB[half][0][srow][skq]     = vb0;
        *(bf16x8*)&sB[half][0][srow][skq + 8] = vb1;
        va0 = *(const bf16x8*)(pA + 64); va1 = *(const bf16x8*)(pA + 72);
        vb0 = *(const bf16x8*)(pB + 64); vb1 = *(const bf16x8*)(pB + 72);
        __syncthreads();
        for (int k0 = 0; k0 < 512; k0 += 64) {
            const int bb = (k0 >> 6) & 1;
            bf16x8 a[2][2], b2[2][2];
            #pragma unroll
            for (int ks = 0; ks < 2; ++ks)
                #pragma unroll
                for (int i = 0; i < 2; ++i) {
                    a[ks][i]  = *(const bf16x8*)&sA[half][bb][wm + i*16 + fm][ks*32 + fk];
                    b2[ks][i] = *(const bf16x8*)&sB[half][bb][wn + i*16 + fm][ks*32 + fk];
                }
            if (k0 + 64 < 512) {
                *(bf16x8*)&sA[half][bb^1][srow][skq]     = va0;
                *(bf16x8*)&sA[half][bb^1][srow][skq + 8] = va1;
                *(bf16x8*)&sB[half][bb^1][srow][skq]     = vb0;
                *(bf16x8*)&sB[half][bb^1][srow][skq + 8] = vb1;
            }
            if (k0 + 128 < 512) {
                va0 = *(const bf16x8*)(pA + k0 + 128); va1 = *(const bf16x8*)(pA + k0 + 136);
                vb0 = *(const bf16x8*)(pB + k0 + 128); vb1 = *(const bf16x8*)(pB + k0 + 136);
            }
            #pragma unroll
            for (int ks = 0; ks < 2; ++ks)
                #pragma unroll
                for (int i = 0; i < 2; ++i)
                    #pragma unroll
                    for (int j = 0; j < 2; ++j)
                        acc[i][j] = mfma1(a[ks][i], b2[ks][j], acc[i][j]);
            __syncthreads();
        }
        __syncthreads();
        if (half == 1) {
            #pragma unroll
            for (int i = 0; i < 2; ++i)
                #pragma unroll
                for (int j = 0; j < 2; ++j)
                    *(f32x4*)&sRed[ht][(i*2 + j) * 4] = acc[i][j];
        }
        __syncthreads();
        if (half == 0) {
            const int crow0 = (lane >> 4) * 4, ccol = lane & 15;
            #pragma unroll
            for (int i = 0; i < 2; ++i)
                #pragma unroll
                for (int j = 0; j < 2; ++j) {
                    f32x4 p = *(const f32x4*)&sRed[ht][(i*2 + j) * 4];
                    #pragma unroll
                    for (int r = 0; r < 4; ++r)
                        out[(size_t)(bm + wm + i*16 + crow0 + r) * 1024 + bn + wn + j*16 + ccol] =
                            acc[i][j][r] + p[r];
                }
        }
    }
}

extern "C" void kernel_launch(void* const* d_in, const int* in_sizes, int n_in,
                              void* d_out, int out_size, void* d_ws, size_t ws_size,
                              hipStream_t stream) {
    const float* hs = (const float*)d_in[0];
    const float* Wq = (const float*)d_in[1];
    const float* Wk = (const float*)d_in[2];
    const float* Wv = (const float*)d_in[3];
    const float* Wo = (const float*)d_in[4];
    float* out = (float*)d_out;

    char* p = (char*)d_ws;
    short* Cp  = (short*)p; p += (size_t)1024*1536*2;
    short* hsh = (short*)p; p += (size_t)1048576*2;
    short* Wch = (short*)p; p += (size_t)1536*1024*2;
    short* Woh = (short*)p; p += (size_t)1048576*2;
    short* S   = (short*)p; p += (size_t)32*NC*CH*DP*2;
    float* Z   = (float*)p; p += (size_t)32*NC*DP*4;
    short* Y   = (short*)p; p += (size_t)1048576*2;
    unsigned* bar = (unsigned*)p; p += 256;

    barinit<<<dim3(1), dim3(64), 0, stream>>>(bar);
    fused<<<dim3(256), dim3(512), 0, stream>>>(hs, Wq, Wk, Wv, Wo,
                                               hsh, Wch, Woh, Cp, S, Z, Y, out, bar);
}

// Round 5
// 142.647 us; speedup vs baseline: 3.4426x; 1.2788x over previous
//
#include <hip/hip_runtime.h>

#define T 512
#define B 2
#define NH 16
#define FD 16
#define HD 64
#define DP 160
#define CH 64
#define NC 8

typedef __attribute__((ext_vector_type(4))) short short4v;
typedef __attribute__((ext_vector_type(8))) short bf16x8;
typedef __attribute__((ext_vector_type(4))) float f32x4;
typedef unsigned long long u64;

__constant__ unsigned char c_iu[120] = {
0,0,0,0,0,0,0,0,0,0,0,0,0,0,0,
1,1,1,1,1,1,1,1,1,1,1,1,1,1,
2,2,2,2,2,2,2,2,2,2,2,2,2,
3,3,3,3,3,3,3,3,3,3,3,3,
4,4,4,4,4,4,4,4,4,4,4,
5,5,5,5,5,5,5,5,5,5,
6,6,6,6,6,6,6,6,6,
7,7,7,7,7,7,7,7,
8,8,8,8,8,8,8,
9,9,9,9,9,9,
10,10,10,10,10,
11,11,11,11,
12,12,12,
13,13,
14};
__constant__ unsigned char c_ju[120] = {
1,2,3,4,5,6,7,8,9,10,11,12,13,14,15,
2,3,4,5,6,7,8,9,10,11,12,13,14,15,
3,4,5,6,7,8,9,10,11,12,13,14,15,
4,5,6,7,8,9,10,11,12,13,14,15,
5,6,7,8,9,10,11,12,13,14,15,
6,7,8,9,10,11,12,13,14,15,
7,8,9,10,11,12,13,14,15,
8,9,10,11,12,13,14,15,
9,10,11,12,13,14,15,
10,11,12,13,14,15,
11,12,13,14,15,
12,13,14,15,
13,14,15,
14,15,
15};

__device__ inline unsigned short f2bf_rne(float x) {
    unsigned u = __float_as_uint(x);
    u += 0x7fff + ((u >> 16) & 1);
    return (unsigned short)(u >> 16);
}
__device__ inline float bf2f(unsigned short h) {
    return __uint_as_float(((unsigned)h) << 16);
}
__device__ inline f32x4 mfma1(bf16x8 a, bf16x8 b, f32x4 acc) {
    return __builtin_amdgcn_mfma_f32_16x16x32_bf16(a, b, acc, 0, 0, 0);
}
__device__ inline bf16x8 cvt8(float4 a, float4 b) {
    bf16x8 r;
    r[0]=(short)f2bf_rne(a.x); r[1]=(short)f2bf_rne(a.y);
    r[2]=(short)f2bf_rne(a.z); r[3]=(short)f2bf_rne(a.w);
    r[4]=(short)f2bf_rne(b.x); r[5]=(short)f2bf_rne(b.y);
    r[6]=(short)f2bf_rne(b.z); r[7]=(short)f2bf_rne(b.w);
    return r;
}

// ---- MALL-coherent accessors via BUILTIN relaxed agent atomics (compile to
// sc1-flagged global ops: bypass L1/L2, coherent across XCDs, no fences).
__device__ inline void st_coh_u32(unsigned* p, unsigned v) {
    __hip_atomic_store(p, v, __ATOMIC_RELAXED, __HIP_MEMORY_SCOPE_AGENT);
}
__device__ inline unsigned ld_coh_u32(const unsigned* p) {
    return __hip_atomic_load((unsigned*)p, __ATOMIC_RELAXED, __HIP_MEMORY_SCOPE_AGENT);
}
__device__ inline u64 ld_coh_u64(const void* p) {
    return __hip_atomic_load((u64*)p, __ATOMIC_RELAXED, __HIP_MEMORY_SCOPE_AGENT);
}
// Pair-pack store: lane holds bf16 for column (lane&15); lanes (even,odd) pack
// into one u32 and the even lane stores it. pcol must point at the even column.
__device__ inline void st_pair(short* pcol, unsigned short v, int lane) {
    unsigned x = v;
    unsigned other = (unsigned)__shfl_xor((int)x, 1);
    if ((lane & 1) == 0) st_coh_u32((unsigned*)pcol, x | (other << 16));
}
__device__ inline bf16x8 ld16coh(const short* p) {   // 16B = two u64 coherent loads
    u64 a = ld_coh_u64(p), b = ld_coh_u64(p + 4);
    bf16x8 r;
    r[0]=(short)a; r[1]=(short)(a>>16); r[2]=(short)(a>>32); r[3]=(short)(a>>48);
    r[4]=(short)b; r[5]=(short)(b>>16); r[6]=(short)(b>>32); r[7]=(short)(b>>48);
    return r;
}

// Fence-free grid barrier: vmcnt drain, relaxed arrival on 8 spread counters
// (64B apart; splits MALL RMW serialization), bounded relaxed spin.
__device__ inline void grid_barrier(unsigned* __restrict__ bar, unsigned k) {
    __builtin_amdgcn_s_waitcnt(0);      // all sc1 stores reach MALL (coherence pt)
    __syncthreads();
    if (threadIdx.x == 0) {
        __hip_atomic_fetch_add(&bar[(blockIdx.x & 7) * 16], 1u,
                               __ATOMIC_RELAXED, __HIP_MEMORY_SCOPE_AGENT);
        const unsigned tgt = 32u * k;
        for (unsigned it = 0; it < (1u << 17); ++it) {   // bounded: ~7ms max
            unsigned mn = 0xffffffffu;
            #pragma unroll
            for (int s = 0; s < 8; ++s) {
                unsigned v = ld_coh_u32(&bar[s * 16]);
                mn = v < mn ? v : mn;
            }
            if (mn >= tgt) break;
            __builtin_amdgcn_s_sleep(2);
        }
    }
    __syncthreads();
}

// row-major features
__device__ inline void feat40(const float* __restrict__ x, int q4,
                              unsigned short* __restrict__ dst) {
    #pragma unroll
    for (int g = 0; g < 10; ++g) {
        short4v s;
        #pragma unroll
        for (int e = 0; e < 4; ++e) {
            const int D = q4 * 40 + g * 4 + e;
            float f;
            if (D == 0)       f = 1.f;
            else if (D < 17)  f = x[D-1] * 0.5f;
            else if (D < 33)  { float a = x[D-17]; f = a * a * 0.17677669529663687f; }
            else if (D < 153) { int p = D - 33; f = x[c_iu[p]] * x[c_ju[p]] * 0.25f; }
            else              f = 0.f;
            s[e] = (short)f2bf_rne(f);
        }
        *(short4v*)(dst + q4 * 40 + g * 4) = s;
    }
}

// transposed features
__device__ inline void feat40T(const float* __restrict__ x, int q4, int r,
                               unsigned short (*KT)[72]) {
    #pragma unroll
    for (int g = 0; g < 10; ++g) {
        #pragma unroll
        for (int e = 0; e < 4; ++e) {
            const int D = q4 * 40 + g * 4 + e;
            float f;
            if (D == 0)       f = 1.f;
            else if (D < 17)  f = x[D-1] * 0.5f;
            else if (D < 33)  { float a = x[D-17]; f = a * a * 0.17677669529663687f; }
            else if (D < 153) { int p = D - 33; f = x[c_iu[p]] * x[c_ju[p]] * 0.25f; }
            else              f = 0.f;
            KT[D][r] = f2bf_rne(f);
        }
    }
}

// Flush every XCD's L2 of dirty lines (the harness's workspace poison-fill!)
// so later evictions cannot overwrite our MALL-coherent data. One release
// fence (buffer_wbl2) per block; 64 blocks round-robin over 8 XCDs.
__global__ void wsflush() {
    if (threadIdx.x == 0) __builtin_amdgcn_fence(__ATOMIC_RELEASE, "agent");
}
// Zero the 8 barrier slots with coherent stores (runs AFTER wsflush).
__global__ void barinit(unsigned* __restrict__ bar) {
    if (threadIdx.x < 8) st_coh_u32(&bar[threadIdx.x * 16], 0u);
}

// ============================================================================
// FUSED persistent kernel, 4 phases, 3 fence-free barriers.
// Cross-phase buffers (Cp, S, Z, Y) accessed EXCLUSIVELY via relaxed agent
// atomics (sc1 / MALL-coherent). Inputs normally cached. f32->bf16 fused
// into GEMM staging (preconv eliminated).
// ============================================================================
__global__ __launch_bounds__(512)
void fused(const float* __restrict__ hs, const float* __restrict__ Wq,
           const float* __restrict__ Wk, const float* __restrict__ Wv,
           const float* __restrict__ Wo,
           short* __restrict__ Cp, short* __restrict__ S, float* __restrict__ Z,
           short* __restrict__ Y, float* __restrict__ out,
           unsigned* __restrict__ bar) {
    __shared__ __align__(16) char smem[116736];
    const int tid = threadIdx.x;
    const int bid = blockIdx.x;

    // ---------------- phase 1: gemm_proj  Cp = bf16(hs) @ bf16(W)^T ----------
    {
        short (*sA)[2][64][72] = (short(*)[2][64][72])(smem);
        short (*sB)[2][96][72] = (short(*)[2][96][72])(smem + 36864);
        float (*sRed)[24]      = (float(*)[24])(smem + 92160);
        const int half = tid >> 8;
        const int ht = tid & 255;
        const int bm = (bid >> 4) * 64, bn = (bid & 15) * 96;
        const int lane = ht & 63, w2 = ht >> 6;
        const int wm = (w2 & 1) * 32, wn = (w2 >> 1) * 48;
        const int srA = ht >> 2, skA = (ht & 3) * 16;
        const int srB = ht >> 1, skB = (ht & 1) * 32;
        const int fm = lane & 15, fk = (lane >> 4) * 8;
        const int kbase = half * 512;
        f32x4 acc[2][3] = {};
        const float* pA = hs + (size_t)(bm + srA) * 1024 + kbase + skA;
        const int Rb = bn + (srB < 96 ? srB : 0);
        const float* wsrc = (Rb < 256) ? (Wq + (size_t)Rb * 1024)
                          : (Rb < 512) ? (Wk + (size_t)(Rb - 256) * 1024)
                                       : (Wv + (size_t)(Rb - 512) * 1024);
        const float* pB = wsrc + kbase + skB;
        float4 qa0, qa1, qa2, qa3;
        float4 qb0, qb1, qb2, qb3, qb4, qb5, qb6, qb7;
        qa0 = *(const float4*)pA;        qa1 = *(const float4*)(pA + 4);
        qa2 = *(const float4*)(pA + 8);  qa3 = *(const float4*)(pA + 12);
        if (ht < 192) {
            qb0 = *(const float4*)pB;        qb1 = *(const float4*)(pB + 4);
            qb2 = *(const float4*)(pB + 8);  qb3 = *(const float4*)(pB + 12);
            qb4 = *(const float4*)(pB + 16); qb5 = *(const float4*)(pB + 20);
            qb6 = *(const float4*)(pB + 24); qb7 = *(const float4*)(pB + 28);
        }
        *(bf16x8*)&sA[half][0][srA][skA]     = cvt8(qa0, qa1);
        *(bf16x8*)&sA[half][0][srA][skA + 8] = cvt8(qa2, qa3);
        if (ht < 192) {
            *(bf16x8*)&sB[half][0][srB][skB]      = cvt8(qb0, qb1);
            *(bf16x8*)&sB[half][0][srB][skB + 8]  = cvt8(qb2, qb3);
            *(bf16x8*)&sB[half][0][srB][skB + 16] = cvt8(qb4, qb5);
            *(bf16x8*)&sB[half][0][srB][skB + 24] = cvt8(qb6, qb7);
        }
        qa0 = *(const float4*)(pA + 64); qa1 = *(const float4*)(pA + 68);
        qa2 = *(const float4*)(pA + 72); qa3 = *(const float4*)(pA + 76);
        if (ht < 192) {
            qb0 = *(const float4*)(pB + 64); qb1 = *(const float4*)(pB + 68);
            qb2 = *(const float4*)(pB + 72); qb3 = *(const float4*)(pB + 76);
            qb4 = *(const float4*)(pB + 80); qb5 = *(const float4*)(pB + 84);
            qb6 = *(const float4*)(pB + 88); qb7 = *(const float4*)(pB + 92);
        }
        __syncthreads();
        for (int k0 = 0; k0 < 512; k0 += 64) {
            const int bb = (k0 >> 6) & 1;
            bf16x8 a[2][2], bfr[2][3];
            #pragma unroll
            for (int ks = 0; ks < 2; ++ks) {
                #pragma unroll
                for (int i = 0; i < 2; ++i)
                    a[ks][i] = *(const bf16x8*)&sA[half][bb][wm + i*16 + fm][ks*32 + fk];
                #pragma unroll
                for (int j = 0; j < 3; ++j)
                    bfr[ks][j] = *(const bf16x8*)&sB[half][bb][wn + j*16 + fm][ks*32 + fk];
            }
            if (k0 + 64 < 512) {
                *(bf16x8*)&sA[half][bb^1][srA][skA]     = cvt8(qa0, qa1);
                *(bf16x8*)&sA[half][bb^1][srA][skA + 8] = cvt8(qa2, qa3);
                if (ht < 192) {
                    *(bf16x8*)&sB[half][bb^1][srB][skB]      = cvt8(qb0, qb1);
                    *(bf16x8*)&sB[half][bb^1][srB][skB + 8]  = cvt8(qb2, qb3);
                    *(bf16x8*)&sB[half][bb^1][srB][skB + 16] = cvt8(qb4, qb5);
                    *(bf16x8*)&sB[half][bb^1][srB][skB + 24] = cvt8(qb6, qb7);
                }
            }
            if (k0 + 128 < 512) {
                const float* pA2 = pA + k0 + 128;
                qa0 = *(const float4*)pA2;        qa1 = *(const float4*)(pA2 + 4);
                qa2 = *(const float4*)(pA2 + 8);  qa3 = *(const float4*)(pA2 + 12);
                if (ht < 192) {
                    const float* pB2 = pB + k0 + 128;
                    qb0 = *(const float4*)pB2;        qb1 = *(const float4*)(pB2 + 4);
                    qb2 = *(const float4*)(pB2 + 8);  qb3 = *(const float4*)(pB2 + 12);
                    qb4 = *(const float4*)(pB2 + 16); qb5 = *(const float4*)(pB2 + 20);
                    qb6 = *(const float4*)(pB2 + 24); qb7 = *(const float4*)(pB2 + 28);
                }
            }
            #pragma unroll
            for (int ks = 0; ks < 2; ++ks)
                #pragma unroll
                for (int j = 0; j < 3; ++j)
                    #pragma unroll
                    for (int i = 0; i < 2; ++i)
                        acc[i][j] = mfma1(a[ks][i], bfr[ks][j], acc[i][j]);
            __syncthreads();
        }
        __syncthreads();
        if (half == 1) {
            #pragma unroll
            for (int i = 0; i < 2; ++i)
                #pragma unroll
                for (int j = 0; j < 3; ++j)
                    *(f32x4*)&sRed[ht][(i*3 + j) * 4] = acc[i][j];
        }
        __syncthreads();
        if (half == 0) {
            const int crow0 = (lane >> 4) * 4, ccol = lane & 15;
            #pragma unroll
            for (int i = 0; i < 2; ++i)
                #pragma unroll
                for (int j = 0; j < 3; ++j) {
                    f32x4 o = acc[i][j];
                    f32x4 p = *(const f32x4*)&sRed[ht][(i*3 + j) * 4];
                    #pragma unroll
                    for (int r = 0; r < 4; ++r) {
                        short* pcol = Cp + (size_t)(bm + wm + i*16 + crow0 + r) * 1536
                                         + bn + wn + j*16 + (ccol & ~1);
                        st_pair(pcol, f2bf_rne(o[r] + p[r]), lane);
                    }
                }
        }
    }
    grid_barrier(bar, 1u);

    // ---------------- phase 2: chunk_state (tid<256 active) -------------------
    {
        float (*sKP)[17]          = (float(*)[17])(smem);
        unsigned short (*sKT)[72] = (unsigned short(*)[72])(smem + 4352);
        unsigned short (*sVT)[72] = (unsigned short(*)[72])(smem + 27392);
        const int bh = bid >> 3, c = bid & 7;
        const int b = bh >> 4, h = bh & 15;
        const int lane = tid & 63, w = tid >> 6;
        const int wm = (w & 1) * 32, wn = ((w >> 1) & 1) * 80;
        const int fm = lane & 15, fk = (lane >> 4) * 8;
        const int r = (tid & 255) >> 2, q4 = tid & 3;
        const size_t rowbase = (size_t)(b*T + c*CH + r) * 1536;
        if (tid < 256) {
            u64 kraw = ld_coh_u64(Cp + rowbase + 256 + h*16 + q4*4);
            const short* pv = Cp + rowbase + 512 + h*HD + q4*16;
            u64 v0 = ld_coh_u64(pv), v1 = ld_coh_u64(pv + 4);
            u64 v2 = ld_coh_u64(pv + 8), v3 = ld_coh_u64(pv + 12);
            float4 kf;
            kf.x = bf2f((unsigned short)kraw);
            kf.y = bf2f((unsigned short)(kraw >> 16));
            kf.z = bf2f((unsigned short)(kraw >> 32));
            kf.w = bf2f((unsigned short)(kraw >> 48));
            *(float4*)&sKP[r][q4*4] = kf;
            #pragma unroll
            for (int e = 0; e < 4; ++e) {
                sVT[q4*16 + e][r]      = (unsigned short)(v0 >> (e*16));
                sVT[q4*16 + 4 + e][r]  = (unsigned short)(v1 >> (e*16));
                sVT[q4*16 + 8 + e][r]  = (unsigned short)(v2 >> (e*16));
                sVT[q4*16 + 12 + e][r] = (unsigned short)(v3 >> (e*16));
            }
        }
        __syncthreads();
        if (tid < 256) feat40T(sKP[r], q4, r, sKT);
        __syncthreads();
        if (tid < 256) {
            if (tid < DP) {
                float zz = 0.f;
                #pragma unroll
                for (int blk = 0; blk < 8; ++blk) {
                    bf16x8 v = *(const bf16x8*)&sKT[tid][blk*8];
                    #pragma unroll
                    for (int e = 0; e < 8; ++e) zz += bf2f((unsigned short)v[e]);
                }
                st_coh_u32((unsigned*)(Z + ((size_t)(bh*NC + c)) * DP + tid),
                           __float_as_uint(zz));
            }
            f32x4 acc[2][5] = {};
            #pragma unroll
            for (int k0 = 0; k0 < 64; k0 += 32) {
                bf16x8 a[2];
                #pragma unroll
                for (int i = 0; i < 2; ++i)
                    a[i] = *(const bf16x8*)&sVT[wm + i*16 + fm][k0 + fk];
                #pragma unroll
                for (int j = 0; j < 5; ++j) {
                    bf16x8 bv = *(const bf16x8*)&sKT[wn + j*16 + fm][k0 + fk];
                    #pragma unroll
                    for (int i = 0; i < 2; ++i)
                        acc[i][j] = mfma1(a[i], bv, acc[i][j]);
                }
            }
            const int crow0 = (lane >> 4) * 4, ccol = lane & 15;
            short* Sb = S + ((size_t)(bh*NC + c)) * CH * DP;
            #pragma unroll
            for (int i = 0; i < 2; ++i)
                #pragma unroll
                for (int j = 0; j < 5; ++j)
                    #pragma unroll
                    for (int rr = 0; rr < 4; ++rr) {
                        short* pcol = Sb + (size_t)(wm + i*16 + crow0 + rr) * DP
                                         + wn + j*16 + (ccol & ~1);
                        st_pair(pcol, f2bf_rne(acc[i][j][rr]), lane);
                    }
        }
    }
    grid_barrier(bar, 2u);

    // ---------------- phase 3: chunk_out (tid<256 active) ---------------------
    {
        float (*sQP)[17]          = (float(*)[17])(smem);
        float (*sKP)[17]          = (float(*)[17])(smem + 4352);
        unsigned short (*sQf)[168]= (unsigned short(*)[168])(smem + 8704);
        unsigned short (*sKf)[168]= (unsigned short(*)[168])(smem + 30208);
        unsigned short (*sPb)[168]= (unsigned short(*)[168])(smem + 51712);
        unsigned short (*sAb)[72] = (unsigned short(*)[72])(smem + 73216);
        unsigned short (*sVT)[72] = (unsigned short(*)[72])(smem + 82432);
        float* sZp  = (float*)(smem + 91648);
        float* sDen = (float*)(smem + 92288);
        const int bh = bid >> 3, c = bid & 7;
        const int b = bh >> 4, h = bh & 15;
        const int lane = tid & 63, w = tid >> 6;
        const int wm = (w & 1) * 32, wn = ((w >> 1) & 1) * 32;
        const int fm = lane & 15, fk = (lane >> 4) * 8;
        const int r = (tid & 255) >> 2, q4 = tid & 3;
        const int crow0 = (lane >> 4) * 4, ccol = lane & 15;
        const size_t rowbase = (size_t)(b*T + c*CH + r) * 1536;
        f32x4 accA[2][2] = {};
        f32x4 accI[2][2] = {};
        if (tid < 256) {
            u64 qraw = ld_coh_u64(Cp + rowbase + h*16 + q4*4);
            u64 kraw = ld_coh_u64(Cp + rowbase + 256 + h*16 + q4*4);
            const short* pv = Cp + rowbase + 512 + h*HD + q4*16;
            u64 v0 = ld_coh_u64(pv), v1 = ld_coh_u64(pv + 4);
            u64 v2 = ld_coh_u64(pv + 8), v3 = ld_coh_u64(pv + 12);
            float4 qf, kf;
            qf.x = bf2f((unsigned short)qraw);
            qf.y = bf2f((unsigned short)(qraw >> 16));
            qf.z = bf2f((unsigned short)(qraw >> 32));
            qf.w = bf2f((unsigned short)(qraw >> 48));
            kf.x = bf2f((unsigned short)kraw);
            kf.y = bf2f((unsigned short)(kraw >> 16));
            kf.z = bf2f((unsigned short)(kraw >> 32));
            kf.w = bf2f((unsigned short)(kraw >> 48));
            *(float4*)&sQP[r][q4*4] = qf;
            *(float4*)&sKP[r][q4*4] = kf;
            #pragma unroll
            for (int e = 0; e < 4; ++e) {
                sVT[q4*16 + e][r]      = (unsigned short)(v0 >> (e*16));
                sVT[q4*16 + 4 + e][r]  = (unsigned short)(v1 >> (e*16));
                sVT[q4*16 + 8 + e][r]  = (unsigned short)(v2 >> (e*16));
                sVT[q4*16 + 12 + e][r] = (unsigned short)(v3 >> (e*16));
            }
            if (tid < DP) {
                float zz = 0.f;
                #pragma unroll
                for (int cc = 0; cc < 7; ++cc)
                    if (cc < c)
                        zz += __uint_as_float(ld_coh_u32(
                            (const unsigned*)(Z + ((size_t)(bh*NC + cc)) * DP + tid)));
                sZp[tid] = zz;
            }
        }
        __syncthreads();
        if (tid < 256) {
            feat40(sQP[r], q4, (unsigned short*)sQf[r]);
            feat40(sKP[r], q4, (unsigned short*)sKf[r]);
            // S-prefix: cc-outer, 5 granules/thread, 10 independent u64 loads/cc
            int dA[5], oA[5];
            #pragma unroll
            for (int s = 0; s < 5; ++s) {
                int e = tid + s * 256; dA[s] = e / 20; oA[s] = (e % 20) * 8;
            }
            float acc5[5][8] = {};
            for (int cc = 0; cc < c; ++cc) {
                const short* sb = S + ((size_t)(bh*NC + cc)) * CH * DP;
                u64 raw[10];
                #pragma unroll
                for (int s = 0; s < 5; ++s) {
                    const short* ps = sb + (size_t)dA[s] * DP + oA[s];
                    raw[2*s]   = ld_coh_u64(ps);
                    raw[2*s+1] = ld_coh_u64(ps + 4);
                }
                #pragma unroll
                for (int s = 0; s < 5; ++s)
                    #pragma unroll
                    for (int q = 0; q < 2; ++q)
                        #pragma unroll
                        for (int e2 = 0; e2 < 4; ++e2)
                            acc5[s][q*4 + e2] +=
                                bf2f((unsigned short)(raw[2*s+q] >> (e2*16)));
            }
            #pragma unroll
            for (int s = 0; s < 5; ++s) {
                bf16x8 o;
                #pragma unroll
                for (int e2 = 0; e2 < 8; ++e2) o[e2] = (short)f2bf_rne(acc5[s][e2]);
                *(bf16x8*)&sPb[dA[s]][oA[s]] = o;
            }
        }
        __syncthreads();
        if (tid < 256) {
            for (int k0 = 0; k0 < DP; k0 += 32) {
                bf16x8 qv[2];
                #pragma unroll
                for (int i = 0; i < 2; ++i)
                    qv[i] = *(const bf16x8*)&sQf[wm + i*16 + fm][k0 + fk];
                #pragma unroll
                for (int j = 0; j < 2; ++j) {
                    bf16x8 kv = *(const bf16x8*)&sKf[wn + j*16 + fm][k0 + fk];
                    bf16x8 pv = *(const bf16x8*)&sPb[wn + j*16 + fm][k0 + fk];
                    #pragma unroll
                    for (int i = 0; i < 2; ++i) {
                        accA[i][j] = mfma1(qv[i], kv, accA[i][j]);
                        accI[i][j] = mfma1(qv[i], pv, accI[i][j]);
                    }
                }
            }
            {
                float dp = 0.f;
                #pragma unroll
                for (int g = 0; g < 5; ++g) {
                    bf16x8 v = *(const bf16x8*)&sQf[r][q4*40 + g*8];
                    #pragma unroll
                    for (int e = 0; e < 8; ++e)
                        dp += bf2f((unsigned short)v[e]) * sZp[q4*40 + g*8 + e];
                }
                dp += __shfl_xor(dp, 1);
                dp += __shfl_xor(dp, 2);
                if (q4 == 0) sDen[r] = dp;
            }
            #pragma unroll
            for (int i = 0; i < 2; ++i)
                #pragma unroll
                for (int j = 0; j < 2; ++j)
                    #pragma unroll
                    for (int rr = 0; rr < 4; ++rr) {
                        const int t_ = wm + i*16 + crow0 + rr, s_ = wn + j*16 + ccol;
                        sAb[t_][s_] = (s_ <= t_) ? f2bf_rne(accA[i][j][rr]) : 0;
                    }
        }
        __syncthreads();
        if (tid < 256) {
            float rs = 0.f;
            bf16x8 v0 = *(const bf16x8*)&sAb[r][q4*16];
            bf16x8 v1 = *(const bf16x8*)&sAb[r][q4*16 + 8];
            #pragma unroll
            for (int e = 0; e < 8; ++e)
                rs += bf2f((unsigned short)v0[e]) + bf2f((unsigned short)v1[e]);
            rs += __shfl_xor(rs, 1);
            rs += __shfl_xor(rs, 2);
            if (q4 == 0) sDen[r] += rs;
        }
        __syncthreads();
        if (tid < 256) {
            #pragma unroll
            for (int k0 = 0; k0 < 64; k0 += 32) {
                bf16x8 a[2];
                #pragma unroll
                for (int i = 0; i < 2; ++i)
                    a[i] = *(const bf16x8*)&sAb[wm + i*16 + fm][k0 + fk];
                #pragma unroll
                for (int j = 0; j < 2; ++j) {
                    bf16x8 bv = *(const bf16x8*)&sVT[wn + j*16 + fm][k0 + fk];
                    #pragma unroll
                    for (int i = 0; i < 2; ++i)
                        accI[i][j] = mfma1(a[i], bv, accI[i][j]);
                }
            }
            #pragma unroll
            for (int i = 0; i < 2; ++i)
                #pragma unroll
                for (int rr = 0; rr < 4; ++rr) {
                    const int t_ = wm + i*16 + crow0 + rr;
                    const float inv = 1.f / (sDen[t_] + 1e-12f);
                    const size_t grow = (size_t)(b*T + c*CH + t_) * 1024 + h*HD;
                    #pragma unroll
                    for (int j = 0; j < 2; ++j) {
                        short* pcol = Y + grow + wn + j*16 + (ccol & ~1);
                        st_pair(pcol, f2bf_rne(accI[i][j][rr] * inv), lane);
                    }
                }
        }
    }
    grid_barrier(bar, 3u);

    // ---------------- phase 4: gemm_out  out = Y @ bf16(Wo)^T ----------------
    {
        short (*sA)[2][64][72] = (short(*)[2][64][72])(smem);
        short (*sB)[2][64][72] = (short(*)[2][64][72])(smem + 36864);
        float (*sRed)[16]      = (float(*)[16])(smem + 73728);
        const int half = tid >> 8;
        const int ht = tid & 255;
        const int bm = (bid >> 4) * 64, bn = (bid & 15) * 64;
        const int lane = ht & 63, w2 = ht >> 6;
        const int wm = (w2 & 1) * 32, wn = (w2 >> 1) * 32;
        const int srow = ht >> 2, skq = (ht & 3) * 16;
        const int fm = lane & 15, fk = (lane >> 4) * 8;
        const int kbase = half * 512;
        f32x4 acc[2][2] = {};
        const short* pA = Y  + (size_t)(bm + srow) * 1024 + kbase + skq;
        const float* pB = Wo + (size_t)(bn + srow) * 1024 + kbase + skq;
        bf16x8 va0, va1;
        float4 qb0, qb1, qb2, qb3;
        va0 = ld16coh(pA); va1 = ld16coh(pA + 8);
        qb0 = *(const float4*)pB;        qb1 = *(const float4*)(pB + 4);
        qb2 = *(const float4*)(pB + 8);  qb3 = *(const float4*)(pB + 12);
        *(bf16x8*)&sA[half][0][srow][skq]     = va0;
        *(bf16x8*)&sA[half][0][srow][skq + 8] = va1;
        *(bf16x8*)&sB[half][0][srow][skq]     = cvt8(qb0, qb1);
        *(bf16x8*)&sB[half][0][srow][skq + 8] = cvt8(qb2, qb3);
        va0 = ld16coh(pA + 64); va1 = ld16coh(pA + 72);
        qb0 = *(const float4*)(pB + 64); qb1 = *(const float4*)(pB + 68);
        qb2 = *(const float4*)(pB + 72); qb3 = *(const float4*)(pB + 76);
        __syncthreads();
        for (int k0 = 0; k0 < 512; k0 += 64) {
            const int bb = (k0 >> 6) & 1;
            bf16x8 a[2][2], b2[2][2];
            #pragma unroll
            for (int ks = 0; ks < 2; ++ks)
                #pragma unroll
                for (int i = 0; i < 2; ++i) {
                    a[ks][i]  = *(const bf16x8*)&sA[half][bb][wm + i*16 + fm][ks*32 + fk];
                    b2[ks][i] = *(const bf16x8*)&sB[half][bb][wn + i*16 + fm][ks*32 + fk];
                }
            if (k0 + 64 < 512) {
                *(bf16x8*)&sA[half][bb^1][srow][skq]     = va0;
                *(bf16x8*)&sA[half][bb^1][srow][skq + 8] = va1;
                *(bf16x8*)&sB[half][bb^1][srow][skq]     = cvt8(qb0, qb1);
                *(bf16x8*)&sB[half][bb^1][srow][skq + 8] = cvt8(qb2, qb3);
            }
            if (k0 + 128 < 512) {
                va0 = ld16coh(pA + k0 + 128); va1 = ld16coh(pA + k0 + 136);
                const float* pB2 = pB + k0 + 128;
                qb0 = *(const float4*)pB2;       qb1 = *(const float4*)(pB2 + 4);
                qb2 = *(const float4*)(pB2 + 8); qb3 = *(const float4*)(pB2 + 12);
            }
            #pragma unroll
            for (int ks = 0; ks < 2; ++ks)
                #pragma unroll
                for (int i = 0; i < 2; ++i)
                    #pragma unroll
                    for (int j = 0; j < 2; ++j)
                        acc[i][j] = mfma1(a[ks][i], b2[ks][j], acc[i][j]);
            __syncthreads();
        }
        __syncthreads();
        if (half == 1) {
            #pragma unroll
            for (int i = 0; i < 2; ++i)
                #pragma unroll
                for (int j = 0; j < 2; ++j)
                    *(f32x4*)&sRed[ht][(i*2 + j) * 4] = acc[i][j];
        }
        __syncthreads();
        if (half == 0) {
            const int crow0 = (lane >> 4) * 4, ccol = lane & 15;
            #pragma unroll
            for (int i = 0; i < 2; ++i)
                #pragma unroll
                for (int j = 0; j < 2; ++j) {
                    f32x4 p = *(const f32x4*)&sRed[ht][(i*2 + j) * 4];
                    #pragma unroll
                    for (int r = 0; r < 4; ++r)
                        out[(size_t)(bm + wm + i*16 + crow0 + r) * 1024 + bn + wn + j*16 + ccol] =
                            acc[i][j][r] + p[r];
                }
        }
    }
}

extern "C" void kernel_launch(void* const* d_in, const int* in_sizes, int n_in,
                              void* d_out, int out_size, void* d_ws, size_t ws_size,
                              hipStream_t stream) {
    const float* hs = (const float*)d_in[0];
    const float* Wq = (const float*)d_in[1];
    const float* Wk = (const float*)d_in[2];
    const float* Wv = (const float*)d_in[3];
    const float* Wo = (const float*)d_in[4];
    float* out = (float*)d_out;

    char* p = (char*)d_ws;
    short* Cp  = (short*)p; p += (size_t)1024*1536*2;
    short* S   = (short*)p; p += (size_t)32*NC*CH*DP*2;
    float* Z   = (float*)p; p += (size_t)32*NC*DP*4;
    short* Y   = (short*)p; p += (size_t)1048576*2;
    unsigned* bar = (unsigned*)p; p += 1024;

    wsflush<<<dim3(64), dim3(64), 0, stream>>>();
    barinit<<<dim3(1), dim3(64), 0, stream>>>(bar);
    fused<<<dim3(256), dim3(512), 0, stream>>>(hs, Wq, Wk, Wv, Wo,
                                               Cp, S, Z, Y, out, bar);
}